// Round 4
// baseline (199.147 us; speedup 1.0000x reference)
//
#include <hip/hip_runtime.h>

// B=262144 batches; per batch solve min ||A w - r||, A=[-x1,-x2,-x3,1] (32x4), r=x0.
// Normal equations via 13 running sums + 4x4 Cholesky.
// R4: no LDS, no barrier. Quad-cooperative: 4 lanes per batch, each lane loads
// 8 rows as 64B-contiguous-per-quad dwordx4 (full-line sectors, zero over-fetch),
// loads pipeline in VGPRs, DPP quad reduce, redundant solve, sub==0 stores.
// pad_mask (d_in[1]) unused by the reference.

__global__ __launch_bounds__(256) void basicls_kernel(const float* __restrict__ x,
                                                      float* __restrict__ out) {
    const int tid  = threadIdx.x;
    const int lane = tid & 63;
    const int wv   = tid >> 6;         // wave 0..3
    const int g    = lane >> 2;        // quad 0..15 within wave
    const int sub  = lane & 3;         // lane within quad

    const int batch = blockIdx.x * 64 + wv * 16 + g;
    const float4* __restrict__ xb = reinterpret_cast<const float4*>(x) + (size_t)batch * 32;

    // Lane reads rows m = 4j + sub: quad covers rows 4j..4j+3 => one contiguous
    // 64 B segment per quad per step. 8 independent dwordx4 loads, no barrier.
    float4 v[8];
#pragma unroll
    for (int j = 0; j < 8; ++j) {
        v[j] = xb[4 * j + sub];
    }

    float s11 = 0.f, s12 = 0.f, s13 = 0.f, s22 = 0.f, s23 = 0.f, s33 = 0.f;
    float s1 = 0.f, s2 = 0.f, s3 = 0.f;
    float t1 = 0.f, t2 = 0.f, t3 = 0.f, t0 = 0.f;

#pragma unroll
    for (int j = 0; j < 8; ++j) {
        float r  = v[j].x;
        float a1 = v[j].y, a2 = v[j].z, a3 = v[j].w;
        s11 = fmaf(a1, a1, s11);
        s12 = fmaf(a1, a2, s12);
        s13 = fmaf(a1, a3, s13);
        s22 = fmaf(a2, a2, s22);
        s23 = fmaf(a2, a3, s23);
        s33 = fmaf(a3, a3, s33);
        s1 += a1; s2 += a2; s3 += a3;
        t1 = fmaf(a1, r, t1);
        t2 = fmaf(a2, r, t2);
        t3 = fmaf(a3, r, t3);
        t0 += r;
    }

    // Combine partials within each quad (xor 1, xor 2 -> DPP row ops).
#define QUAD_REDUCE(q) \
    q += __shfl_xor(q, 1); \
    q += __shfl_xor(q, 2);
    QUAD_REDUCE(s11) QUAD_REDUCE(s12) QUAD_REDUCE(s13)
    QUAD_REDUCE(s22) QUAD_REDUCE(s23) QUAD_REDUCE(s33)
    QUAD_REDUCE(s1)  QUAD_REDUCE(s2)  QUAD_REDUCE(s3)
    QUAD_REDUCE(t1)  QUAD_REDUCE(t2)  QUAD_REDUCE(t3)
    QUAD_REDUCE(t0)
#undef QUAD_REDUCE

    // Gram matrix G = A^T A, rhs = A^T r. All 4 quad lanes solve redundantly
    // (same wave instruction stream -> zero extra issue cost); sub==0 stores.
    float G[4][4];
    G[0][0] = s11; G[0][1] = s12; G[0][2] = s13; G[0][3] = -s1;
    G[1][0] = s12; G[1][1] = s22; G[1][2] = s23; G[1][3] = -s2;
    G[2][0] = s13; G[2][1] = s23; G[2][2] = s33; G[2][3] = -s3;
    G[3][0] = -s1; G[3][1] = -s2; G[3][2] = -s3; G[3][3] = 32.0f;
    float rhs[4] = { -t1, -t2, -t3, t0 };

    float L[4][4];
#pragma unroll
    for (int k = 0; k < 4; ++k) {
        float d = G[k][k];
#pragma unroll
        for (int j = 0; j < 4; ++j) {
            if (j < k) d = fmaf(-L[k][j], L[k][j], d);
        }
        float lkk = sqrtf(fmaxf(d, 1e-30f));
        L[k][k] = lkk;
        float inv = __frcp_rn(lkk);
#pragma unroll
        for (int i = 0; i < 4; ++i) {
            if (i > k) {
                float s = G[i][k];
#pragma unroll
                for (int j = 0; j < 4; ++j) {
                    if (j < k) s = fmaf(-L[i][j], L[k][j], s);
                }
                L[i][k] = s * inv;
            }
        }
    }

    float y[4];
#pragma unroll
    for (int i = 0; i < 4; ++i) {
        float s = rhs[i];
#pragma unroll
        for (int j = 0; j < 4; ++j) {
            if (j < i) s = fmaf(-L[i][j], y[j], s);
        }
        y[i] = s * __frcp_rn(L[i][i]);
    }

    float wsol[4];
#pragma unroll
    for (int i = 3; i >= 0; --i) {
        float s = y[i];
#pragma unroll
        for (int j = 0; j < 4; ++j) {
            if (j > i) s = fmaf(-L[j][i], wsol[j], s);
        }
        wsol[i] = s * __frcp_rn(L[i][i]);
    }

    if (sub == 0) {
        reinterpret_cast<float4*>(out)[batch] =
            make_float4(wsol[0], wsol[1], wsol[2], wsol[3]);
    }
}

extern "C" void kernel_launch(void* const* d_in, const int* in_sizes, int n_in,
                              void* d_out, int out_size, void* d_ws, size_t ws_size,
                              hipStream_t stream) {
    const float* x = (const float*)d_in[0];
    // d_in[1] = pad_mask: unused by the reference computation.
    float* out = (float*)d_out;
    int B = in_sizes[0] / (32 * 4);        // 262144
    dim3 block(256);
    dim3 grid(B / 64);                     // 4096 blocks, 64 batches each
    basicls_kernel<<<grid, block, 0, stream>>>(x, out);
}